// Round 3
// baseline (14202.107 us; speedup 1.0000x reference)
//
#include <hip/hip_runtime.h>
#include <hip/hip_cooperative_groups.h>
#include <cstddef>

namespace cg = cooperative_groups;

// Decoder: B=64, S=400, T=100, E=512, H=512
// R3: single persistent cooperative kernel for the T=100 scan (3 grid.sync
// per step) replacing 300 sequential launches. Step GEMMs now bf16 MFMA.

#define Bdim 64
#define Sdim 400
#define Tdim 100
#define Edim 512
#define Hdim 512
#define H2   1024
#define H3   1536

typedef __attribute__((ext_vector_type(8))) short          bf16x8;
typedef __attribute__((ext_vector_type(8))) unsigned short u16x8;
typedef __attribute__((ext_vector_type(4))) float          f32x4;

__device__ __forceinline__ float bf2f(unsigned short u) {
    return __uint_as_float(((unsigned int)u) << 16);
}
__device__ __forceinline__ unsigned short f2bf(float f) {
    unsigned int x = __float_as_uint(f);
    x += 0x7fffu + ((x >> 16) & 1u);
    return (unsigned short)(x >> 16);
}
__device__ __forceinline__ float fast_tanh(float x) {
    float e = __expf(2.0f * x);
    return 1.0f - 2.0f / (e + 1.0f);
}
__device__ __forceinline__ float sigm(float x) {
    return 1.0f / (1.0f + __expf(-x));
}

// ---------------- one-time kernels ----------------

__global__ __launch_bounds__(256) void k_init(
    const float* __restrict__ ef, const float* __restrict__ Wi,
    const float* __restrict__ bi, float* __restrict__ h0)
{
    __shared__ float efs[1024];
    int b = blockIdx.x, tid = threadIdx.x;
    for (int i = tid; i < 1024; i += 256) efs[i] = ef[(size_t)b * 1024 + i];
    __syncthreads();
    for (int j = tid; j < 512; j += 256) {
        const float4* w4 = (const float4*)(Wi + (size_t)j * 1024);
        float acc = 0.0f;
        for (int k4 = 0; k4 < 256; k4++) {
            float4 wv = w4[k4];
            int k = k4 << 2;
            acc = fmaf(efs[k],   wv.x, acc);
            acc = fmaf(efs[k+1], wv.y, acc);
            acc = fmaf(efs[k+2], wv.z, acc);
            acc = fmaf(efs[k+3], wv.w, acc);
        }
        h0[(size_t)b * 512 + j] = fast_tanh(acc + bi[j]);
    }
}

__global__ void k_cvt(const float4* __restrict__ in, ushort4* __restrict__ out, int n4) {
    int i = blockIdx.x * blockDim.x + threadIdx.x;
    int stride = gridDim.x * blockDim.x;
    for (; i < n4; i += stride) {
        float4 v = in[i];
        ushort4 u;
        u.x = f2bf(v.x); u.y = f2bf(v.y); u.z = f2bf(v.z); u.w = f2bf(v.w);
        out[i] = u;
    }
}

__global__ __launch_bounds__(512) void k_q0(
    const float* __restrict__ h, const float* __restrict__ Wq,
    float* __restrict__ qbuf)
{
    __shared__ float hs[512];
    int b = blockIdx.x, j = threadIdx.x;
    hs[j] = h[(size_t)b * 512 + j];
    __syncthreads();
    const float4* w4 = (const float4*)(Wq + (size_t)j * 512);
    float acc = 0.0f;
    #pragma unroll 4
    for (int k4 = 0; k4 < 128; k4++) {
        float4 wv = w4[k4];
        int k = k4 << 2;
        acc = fmaf(hs[k],   wv.x, acc);
        acc = fmaf(hs[k+1], wv.y, acc);
        acc = fmaf(hs[k+2], wv.z, acc);
        acc = fmaf(hs[k+3], wv.w, acc);
    }
    qbuf[(size_t)b * 512 + j] = acc;
}

// MFMA bf16 GEMM: C[M][N] = A[M][K] @ B[N][K]^T.  (verified in R2)
__global__ __launch_bounds__(256) void k_mfma_gemm(
    const unsigned short* __restrict__ A0, const unsigned short* __restrict__ A1,
    const unsigned short* __restrict__ A2,
    int ld0, int ld1, int ld2, int s1, int s2,
    const unsigned short* __restrict__ Bw, int ldb,
    float* __restrict__ Cf, unsigned short* __restrict__ Cb, int ldc,
    const float* __restrict__ bias, int K)
{
    __shared__ __attribute__((aligned(16))) unsigned short As[128][40];
    __shared__ __attribute__((aligned(16))) unsigned short Bs[128][40];
    int m0 = blockIdx.x << 7, n0 = blockIdx.y << 7;
    int tid = threadIdx.x;
    int wave = tid >> 6, lane = tid & 63;
    int wr = (wave >> 1) << 6, wc = (wave & 1) << 6;
    int fr = lane & 15, fq = lane >> 4;
    f32x4 acc[4][4];
    #pragma unroll
    for (int i = 0; i < 4; i++)
        #pragma unroll
        for (int j = 0; j < 4; j++)
            acc[i][j] = (f32x4){0.f, 0.f, 0.f, 0.f};
    int lrow = tid >> 1;
    int lk = (tid & 1) << 4;
    for (int k0 = 0; k0 < K; k0 += 32) {
        const unsigned short* Ap; int lda_, ka;
        if (k0 < s1)      { Ap = A0; lda_ = ld0; ka = k0; }
        else if (k0 < s2) { Ap = A1; lda_ = ld1; ka = k0 - s1; }
        else              { Ap = A2; lda_ = ld2; ka = k0 - s2; }
        const unsigned short* ap = Ap + (size_t)(m0 + lrow) * lda_ + ka + lk;
        u16x8 av0 = *(const u16x8*)ap;
        u16x8 av1 = *(const u16x8*)(ap + 8);
        const unsigned short* bp_ = Bw + (size_t)(n0 + lrow) * ldb + k0 + lk;
        u16x8 bv0 = *(const u16x8*)bp_;
        u16x8 bv1 = *(const u16x8*)(bp_ + 8);
        __syncthreads();
        *(u16x8*)&As[lrow][lk] = av0;
        *(u16x8*)&As[lrow][lk + 8] = av1;
        *(u16x8*)&Bs[lrow][lk] = bv0;
        *(u16x8*)&Bs[lrow][lk + 8] = bv1;
        __syncthreads();
        bf16x8 af[4], bf[4];
        #pragma unroll
        for (int i = 0; i < 4; i++) {
            af[i] = *(const bf16x8*)&As[wr + (i << 4) + fr][fq << 3];
            bf[i] = *(const bf16x8*)&Bs[wc + (i << 4) + fr][fq << 3];
        }
        #pragma unroll
        for (int i = 0; i < 4; i++)
            #pragma unroll
            for (int j = 0; j < 4; j++)
                acc[i][j] = __builtin_amdgcn_mfma_f32_16x16x32_bf16(af[i], bf[j], acc[i][j], 0, 0, 0);
    }
    #pragma unroll
    for (int j = 0; j < 4; j++) {
        int col = n0 + wc + (j << 4) + fr;
        float bv = bias ? bias[col] : 0.0f;
        #pragma unroll
        for (int i = 0; i < 4; i++) {
            int rbase = m0 + wr + (i << 4) + (fq << 2);
            #pragma unroll
            for (int r = 0; r < 4; r++) {
                float v = acc[i][j][r] + bv;
                if (Cb) Cb[(size_t)(rbase + r) * ldc + col] = f2bf(v);
                else    Cf[(size_t)(rbase + r) * ldc + col] = v;
            }
        }
    }
}

// ---------------- persistent scan kernel ----------------

struct SmemP1 { float eL[104]; float pL[104]; float cbuf[3072]; };
struct SmemP2 {
    unsigned short As[64][264];   // A tile bf16 (rows=b/m, 256 K cols + pad)
    unsigned short Ws[64][72];    // W k-chunk (rows=n, 64 K cols + pad)
    float scS[64][4];
};
struct SmemP3 { float hs[512]; };
union __attribute__((aligned(16))) Smem { SmemP1 p1; SmemP2 p2; SmemP3 p3; };

__global__ __launch_bounds__(512, 1) void k_persist(
    const unsigned short* __restrict__ pkb,
    const unsigned short* __restrict__ ehb,
    const float* __restrict__ We,
    const unsigned short* __restrict__ Wihb,
    const unsigned short* __restrict__ Whhb,
    const unsigned short* __restrict__ Wqb,
    const unsigned short* __restrict__ giEb,
    const float* __restrict__ bih,
    const float* __restrict__ bhh,
    float* __restrict__ qbuf,
    float* __restrict__ hbuf,
    float* __restrict__ mcb,
    float* __restrict__ lcb,
    float* __restrict__ ctxp,
    float* __restrict__ pgi,
    float* __restrict__ pgh,
    unsigned short* __restrict__ csb,
    unsigned short* __restrict__ dsb,
    float* __restrict__ ds,
    float* __restrict__ hlast)
{
    cg::grid_group grid = cg::this_grid();
    __shared__ Smem sm;
    const int bid = blockIdx.x;
    const int tid = threadIdx.x;
    const int wave = tid >> 6, lane = tid & 63;

    for (int t = 0; t < Tdim; t++) {
        // ======== P1: attention (all 256 blocks: c = chunk, b = batch) ========
        {
            int c = bid >> 6, b = bid & 63;
            int s0 = c * 100;
            float q8[8], w8[8];
            {
                const float4* qp = (const float4*)(qbuf + (size_t)b * 512 + (lane << 3));
                float4 q0 = qp[0], q1 = qp[1];
                q8[0]=q0.x; q8[1]=q0.y; q8[2]=q0.z; q8[3]=q0.w;
                q8[4]=q1.x; q8[5]=q1.y; q8[6]=q1.z; q8[7]=q1.w;
                const float4* wp = (const float4*)(We + (lane << 3));
                float4 w0 = wp[0], w1 = wp[1];
                w8[0]=w0.x; w8[1]=w0.y; w8[2]=w0.z; w8[3]=w0.w;
                w8[4]=w1.x; w8[5]=w1.y; w8[6]=w1.z; w8[7]=w1.w;
            }
            for (int sl = wave; sl < 100; sl += 8) {
                u16x8 u = *(const u16x8*)(pkb + ((size_t)b * Sdim + s0 + sl) * 512 + (lane << 3));
                float sum = 0.0f;
                #pragma unroll
                for (int jj = 0; jj < 8; jj++)
                    sum = fmaf(fast_tanh(q8[jj] + bf2f(u[jj])), w8[jj], sum);
                #pragma unroll
                for (int off = 32; off > 0; off >>= 1) sum += __shfl_xor(sum, off, 64);
                if (lane == 0) sm.p1.eL[sl] = sum;
            }
            __syncthreads();
            if (wave == 0) {
                float a0 = (lane < 100) ? sm.p1.eL[lane] : -3.0e38f;
                float a1 = (lane < 36)  ? sm.p1.eL[lane + 64] : -3.0e38f;
                float mx = fmaxf(a0, a1);
                #pragma unroll
                for (int off = 32; off > 0; off >>= 1) mx = fmaxf(mx, __shfl_xor(mx, off, 64));
                float p0 = (lane < 100) ? __expf(a0 - mx) : 0.0f;
                float p1v = (lane < 36) ? __expf(a1 - mx) : 0.0f;
                if (lane < 100) sm.p1.pL[lane] = p0;
                if (lane < 36)  sm.p1.pL[lane + 64] = p1v;
                float s = p0 + p1v;
                #pragma unroll
                for (int off = 32; off > 0; off >>= 1) s += __shfl_xor(s, off, 64);
                if (lane == 0) { mcb[b * 4 + c] = mx; lcb[b * 4 + c] = s; }
            }
            __syncthreads();
            // context partial: 4 row-groups x 128 threads x 8 dims
            int g = tid >> 7, d0 = (tid & 127) << 3;
            float a[8] = {};
            const unsigned short* eb = ehb + ((size_t)b * Sdim + s0) * 1024 + d0;
            for (int sl = g; sl < 100; sl += 4) {
                float pp = sm.p1.pL[sl];
                u16x8 u = *(const u16x8*)(eb + (size_t)sl * 1024);
                #pragma unroll
                for (int jj = 0; jj < 8; jj++) a[jj] = fmaf(pp, bf2f(u[jj]), a[jj]);
            }
            if (g) {
                #pragma unroll
                for (int jj = 0; jj < 8; jj++) sm.p1.cbuf[(g - 1) * 1024 + d0 + jj] = a[jj];
            }
            __syncthreads();
            if (!g) {
                #pragma unroll
                for (int jj = 0; jj < 8; jj++)
                    a[jj] += sm.p1.cbuf[d0 + jj] + sm.p1.cbuf[1024 + d0 + jj] + sm.p1.cbuf[2048 + d0 + jj];
                float4 v0 = make_float4(a[0], a[1], a[2], a[3]);
                float4 v1 = make_float4(a[4], a[5], a[6], a[7]);
                float* op = ctxp + ((size_t)(b * 4 + c)) * 1024 + d0;
                *(float4*)op = v0;
                *(float4*)(op + 4) = v1;
            }
        }
        grid.sync();
        // ======== P2: GRU GEMMs via MFMA (blocks 0..143) ========
        if (bid < 144) {
            bool isGi = bid < 96;
            int kc, nb;
            if (isGi) { kc = bid / 24; nb = bid - kc * 24; }
            else      { int x = bid - 96; kc = x / 24; nb = x - kc * 24; }
            int n0 = nb << 6;
            if (isGi && tid < 64) {
                int b = tid;
                float m0 = mcb[b*4], m1 = mcb[b*4+1], m2 = mcb[b*4+2], m3 = mcb[b*4+3];
                float m = fmaxf(fmaxf(m0, m1), fmaxf(m2, m3));
                float e0 = __expf(m0-m), e1 = __expf(m1-m), e2 = __expf(m2-m), e3 = __expf(m3-m);
                float inv = 1.0f / (e0*lcb[b*4] + e1*lcb[b*4+1] + e2*lcb[b*4+2] + e3*lcb[b*4+3]);
                sm.p2.scS[b][0] = e0*inv; sm.p2.scS[b][1] = e1*inv;
                sm.p2.scS[b][2] = e2*inv; sm.p2.scS[b][3] = e3*inv;
            }
            __syncthreads();
            int r = tid >> 3, c0 = (tid & 7) << 5;
            if (isGi) {
                float s0 = sm.p2.scS[r][0], s1 = sm.p2.scS[r][1];
                float s2 = sm.p2.scS[r][2], s3 = sm.p2.scS[r][3];
                const float* pc = ctxp + (size_t)r * 4096 + (kc << 8) + c0;
                for (int k = 0; k < 32; k += 4) {
                    float4 v0 = *(const float4*)(pc + k);
                    float4 v1 = *(const float4*)(pc + 1024 + k);
                    float4 v2 = *(const float4*)(pc + 2048 + k);
                    float4 v3 = *(const float4*)(pc + 3072 + k);
                    float cx = fmaf(s0, v0.x, fmaf(s1, v1.x, fmaf(s2, v2.x, s3 * v3.x)));
                    float cy = fmaf(s0, v0.y, fmaf(s1, v1.y, fmaf(s2, v2.y, s3 * v3.y)));
                    float cz = fmaf(s0, v0.z, fmaf(s1, v1.z, fmaf(s2, v2.z, s3 * v3.z)));
                    float cw = fmaf(s0, v0.w, fmaf(s1, v1.w, fmaf(s2, v2.w, s3 * v3.w)));
                    ushort4 u;
                    u.x = f2bf(cx); u.y = f2bf(cy); u.z = f2bf(cz); u.w = f2bf(cw);
                    *(ushort4*)&sm.p2.As[r][c0 + k] = u;
                    if (nb == 0)
                        *(ushort4*)&csb[((size_t)r * Tdim + t) * H2 + (kc << 8) + c0 + k] = u;
                }
            } else {
                const float* ph = hbuf + (size_t)r * 512 + (kc << 8) + c0;
                for (int k = 0; k < 32; k += 4) {
                    float4 v = *(const float4*)(ph + k);
                    ushort4 u;
                    u.x = f2bf(v.x); u.y = f2bf(v.y); u.z = f2bf(v.z); u.w = f2bf(v.w);
                    *(ushort4*)&sm.p2.As[r][c0 + k] = u;
                }
            }
            __syncthreads();
            const unsigned short* Wsrc = isGi ? (Wihb + (size_t)n0 * H3 + 512 + (kc << 8))
                                              : (Whhb + (size_t)n0 * Hdim + (kc << 8));
            int ldw = isGi ? H3 : Hdim;
            int fr = lane & 15, fq = lane >> 4;
            int fi = wave >> 1, fj0 = (wave & 1) << 1;
            f32x4 acc0 = {0.f,0.f,0.f,0.f}, acc1 = {0.f,0.f,0.f,0.f};
            int rw = tid >> 3, cw2 = (tid & 7) << 3;
            for (int ch = 0; ch < 4; ch++) {
                __syncthreads();
                u16x8 wv8 = *(const u16x8*)(Wsrc + (size_t)rw * ldw + (ch << 6) + cw2);
                *(u16x8*)&sm.p2.Ws[rw][cw2] = wv8;
                __syncthreads();
                #pragma unroll
                for (int ks = 0; ks < 2; ks++) {
                    bf16x8 af = *(const bf16x8*)&sm.p2.As[(fi << 4) + fr][(ch << 6) + (ks << 5) + (fq << 3)];
                    bf16x8 b0 = *(const bf16x8*)&sm.p2.Ws[(fj0 << 4) + fr][(ks << 5) + (fq << 3)];
                    bf16x8 b1 = *(const bf16x8*)&sm.p2.Ws[((fj0 + 1) << 4) + fr][(ks << 5) + (fq << 3)];
                    acc0 = __builtin_amdgcn_mfma_f32_16x16x32_bf16(af, b0, acc0, 0, 0, 0);
                    acc1 = __builtin_amdgcn_mfma_f32_16x16x32_bf16(af, b1, acc1, 0, 0, 0);
                }
            }
            float* outp = (isGi ? pgi : pgh) + (size_t)kc * Bdim * H3;
            int rowb = (fi << 4) + (fq << 2);
            #pragma unroll
            for (int r4 = 0; r4 < 4; r4++) {
                outp[(size_t)(rowb + r4) * H3 + n0 + (fj0 << 4) + fr] = acc0[r4];
                outp[(size_t)(rowb + r4) * H3 + n0 + ((fj0 + 1) << 4) + fr] = acc1[r4];
            }
        }
        grid.sync();
        // ======== P3: gates + h_new + q_{t+1} (blocks 0..63) ========
        if (bid < 64) {
            int b = bid, j = tid;
            size_t m = (size_t)b * Tdim + t;
            float gir = 0, giz = 0, gin = 0;
            #pragma unroll
            for (int cc = 0; cc < 4; cc++) {
                const float* p = pgi + ((size_t)cc * Bdim + b) * H3;
                gir += p[j]; giz += p[j + 512]; gin += p[j + 1024];
            }
            const unsigned short* ge = giEb + m * H3;
            gir += bf2f(ge[j]); giz += bf2f(ge[j + 512]); gin += bf2f(ge[j + 1024]);
            float ghr = 0, ghz = 0, ghn = 0;
            #pragma unroll
            for (int cc = 0; cc < 2; cc++) {
                const float* p = pgh + ((size_t)cc * Bdim + b) * H3;
                ghr += p[j]; ghz += p[j + 512]; ghn += p[j + 1024];
            }
            gir += bih[j];        ghr += bhh[j];
            giz += bih[j + 512];  ghz += bhh[j + 512];
            gin += bih[j + 1024]; ghn += bhh[j + 1024];
            float rg = sigm(gir + ghr);
            float z  = sigm(giz + ghz);
            float nn = fast_tanh(gin + rg * ghn);
            float hp = hbuf[(size_t)b * 512 + j];
            float hn = (1.0f - z) * nn + z * hp;
            ds[m * 512 + j] = hn;
            dsb[m * 512 + j] = f2bf(hn);
            hbuf[(size_t)b * 512 + j] = hn;
            if (t == Tdim - 1) hlast[(size_t)b * 512 + j] = hn;
            sm.p3.hs[j] = hn;
            __syncthreads();
            const unsigned short* wr_ = Wqb + (size_t)j * 512;
            float acc = 0.0f;
            #pragma unroll 4
            for (int k8 = 0; k8 < 64; k8++) {
                u16x8 wv = *(const u16x8*)(wr_ + (k8 << 3));
                int k = k8 << 3;
                acc = fmaf(sm.p3.hs[k],   bf2f(wv[0]), acc);
                acc = fmaf(sm.p3.hs[k+1], bf2f(wv[1]), acc);
                acc = fmaf(sm.p3.hs[k+2], bf2f(wv[2]), acc);
                acc = fmaf(sm.p3.hs[k+3], bf2f(wv[3]), acc);
                acc = fmaf(sm.p3.hs[k+4], bf2f(wv[4]), acc);
                acc = fmaf(sm.p3.hs[k+5], bf2f(wv[5]), acc);
                acc = fmaf(sm.p3.hs[k+6], bf2f(wv[6]), acc);
                acc = fmaf(sm.p3.hs[k+7], bf2f(wv[7]), acc);
            }
            qbuf[(size_t)b * 512 + j] = acc;
        }
        grid.sync();
    }
}

extern "C" void kernel_launch(void* const* d_in, const int* in_sizes, int n_in,
                              void* d_out, int out_size, void* d_ws, size_t ws_size,
                              hipStream_t stream) {
    const float* te  = (const float*)d_in[0];
    const float* eh  = (const float*)d_in[1];
    const float* ef  = (const float*)d_in[2];
    const float* Wi  = (const float*)d_in[3];
    const float* bi  = (const float*)d_in[4];
    const float* Wk  = (const float*)d_in[5];
    const float* Wq  = (const float*)d_in[6];
    const float* We  = (const float*)d_in[7];
    const float* Wih = (const float*)d_in[8];
    const float* Whh = (const float*)d_in[9];
    const float* bih = (const float*)d_in[10];
    const float* bhh = (const float*)d_in[11];
    const float* Wp  = (const float*)d_in[12];
    const float* bp  = (const float*)d_in[13];

    float* out     = (float*)d_out;
    float* out_ds  = out;
    float* out_hl  = out + (size_t)Bdim * Tdim * Hdim;
    float* out_pre = out_hl + (size_t)Bdim * Hdim;

    // ---- workspace layout ----
    char* w = (char*)d_ws;
    size_t o = 0;
    unsigned short* pkb  = (unsigned short*)(w + o); o += (size_t)25600 * 512 * 2;
    unsigned short* ehb  = (unsigned short*)(w + o); o += (size_t)25600 * 1024 * 2;
    unsigned short* teb  = (unsigned short*)(w + o); o += (size_t)6400 * 512 * 2;
    unsigned short* Wkb  = (unsigned short*)(w + o); o += (size_t)512 * 1024 * 2;
    unsigned short* Wihb = (unsigned short*)(w + o); o += (size_t)1536 * 1536 * 2;
    unsigned short* Whhb = (unsigned short*)(w + o); o += (size_t)1536 * 512 * 2;
    unsigned short* Wpb  = (unsigned short*)(w + o); o += (size_t)512 * 2048 * 2;
    unsigned short* Wqb  = (unsigned short*)(w + o); o += (size_t)512 * 512 * 2;
    unsigned short* dsb  = (unsigned short*)(w + o); o += (size_t)6400 * 512 * 2;
    unsigned short* csb  = (unsigned short*)(w + o); o += (size_t)6400 * 1024 * 2;
    unsigned short* giEb = (unsigned short*)(w + o); o += (size_t)6400 * 1536 * 2;
    float* qbuf = (float*)(w + o); o += (size_t)Bdim * 512 * 4;
    float* hbuf = (float*)(w + o); o += (size_t)Bdim * 512 * 4;
    float* mcb  = (float*)(w + o); o += 256 * 4;
    float* lcb  = (float*)(w + o); o += 256 * 4;
    float* ctxp = (float*)(w + o); o += (size_t)Bdim * 4 * 1024 * 4;
    float* pgi  = (float*)(w + o); o += (size_t)4 * Bdim * H3 * 4;
    float* pgh  = (float*)(w + o); o += (size_t)2 * Bdim * H3 * 4;

    // ---- one-time prep ----
    k_cvt<<<1024, 256, 0, stream>>>((const float4*)eh,  (ushort4*)ehb,  6553600);
    k_cvt<<<512,  256, 0, stream>>>((const float4*)te,  (ushort4*)teb,  819200);
    k_cvt<<<128,  256, 0, stream>>>((const float4*)Wk,  (ushort4*)Wkb,  131072);
    k_cvt<<<256,  256, 0, stream>>>((const float4*)Wih, (ushort4*)Wihb, 589824);
    k_cvt<<<128,  256, 0, stream>>>((const float4*)Whh, (ushort4*)Whhb, 196608);
    k_cvt<<<256,  256, 0, stream>>>((const float4*)Wp,  (ushort4*)Wpb,  262144);
    k_cvt<<<64,   256, 0, stream>>>((const float4*)Wq,  (ushort4*)Wqb,  65536);
    k_init<<<Bdim, 256, 0, stream>>>(ef, Wi, bi, hbuf);
    k_q0<<<Bdim, 512, 0, stream>>>(hbuf, Wq, qbuf);
    k_mfma_gemm<<<dim3(200, 4), 256, 0, stream>>>(
        ehb, ehb, ehb, 1024, 1024, 1024, 1024, 1024,
        Wkb, 1024, nullptr, pkb, 512, nullptr, 1024);
    k_mfma_gemm<<<dim3(50, 12), 256, 0, stream>>>(
        teb, teb, teb, 512, 512, 512, 512, 512,
        Wihb, 1536, nullptr, giEb, 1536, nullptr, 512);

    // ---- persistent cooperative scan ----
    void* args[] = {
        (void*)&pkb, (void*)&ehb, (void*)&We, (void*)&Wihb, (void*)&Whhb,
        (void*)&Wqb, (void*)&giEb, (void*)&bih, (void*)&bhh,
        (void*)&qbuf, (void*)&hbuf, (void*)&mcb, (void*)&lcb, (void*)&ctxp,
        (void*)&pgi, (void*)&pgh, (void*)&csb, (void*)&dsb,
        (void*)&out_ds, (void*)&out_hl
    };
    hipLaunchCooperativeKernel((void*)k_persist, dim3(256), dim3(512), args, 0, stream);

    // ---- final pre-output GEMM ----
    k_mfma_gemm<<<dim3(50, 4), 256, 0, stream>>>(
        teb, dsb, csb, 512, 512, 1024, 512, 1024,
        Wpb, 2048, out_pre, nullptr, 512, bp, 2048);
}

// Round 4
// 6516.721 us; speedup vs baseline: 2.1793x; 2.1793x over previous
//
#include <hip/hip_runtime.h>
#include <cstddef>

// Decoder: B=64, S=400, T=100, E=512, H=512
// R4: multi-launch (3 kernels/step), fp8 e4m3 attention operands (pkb/ehb),
// no-max softmax with cross-dispatch chunk combine, MFMA step GEMMs.

#define Bdim 64
#define Sdim 400
#define Tdim 100
#define Edim 512
#define Hdim 512
#define H2   1024
#define H3   1536

typedef __attribute__((ext_vector_type(8))) short          bf16x8;
typedef __attribute__((ext_vector_type(8))) unsigned short u16x8;
typedef __attribute__((ext_vector_type(4))) float          f32x4;

__device__ __forceinline__ float bf2f(unsigned short u) {
    return __uint_as_float(((unsigned int)u) << 16);
}
__device__ __forceinline__ unsigned short f2bf(float f) {
    unsigned int x = __float_as_uint(f);
    x += 0x7fffu + ((x >> 16) & 1u);
    return (unsigned short)(x >> 16);
}
__device__ __forceinline__ float fast_tanh(float x) {
    float e = __expf(2.0f * x);
    return 1.0f - 2.0f / (e + 1.0f);
}
__device__ __forceinline__ float sigm(float x) {
    return 1.0f / (1.0f + __expf(-x));
}

// ---- OCP e4m3fn encode (software, one-time paths only) ----
__device__ __forceinline__ unsigned char f2fp8(float f) {
    unsigned u = __float_as_uint(f);
    unsigned s = (u >> 24) & 0x80u;
    float a = fabsf(f);
    if (a >= 448.0f) return (unsigned char)(s | 0x7Eu);      // clamp to max
    if (a < 0.0009765625f) return (unsigned char)s;          // < 2^-10 -> 0
    int e = (int)((u >> 23) & 0xFF) - 127;
    if (e < -6) {                                            // fp8 subnormal, step 2^-9
        int q = (int)lrintf(a * 512.0f);                     // 0..8 (8 -> 0x08 normal)
        return (unsigned char)(s | (unsigned)q);
    }
    unsigned mant = u & 0x7FFFFFu;
    unsigned keep = mant >> 20;
    unsigned rem  = mant & 0xFFFFFu;
    if (rem > 0x80000u || (rem == 0x80000u && (keep & 1u))) keep++;
    if (keep == 8u) { keep = 0u; e++; if (e > 8) return (unsigned char)(s | 0x7Eu); }
    return (unsigned char)(s | ((unsigned)(e + 7) << 3) | keep);
}

// ---- fp8 -> f32 decode: HW packed cvt if available ----
#if defined(__has_builtin)
#if __has_builtin(__builtin_amdgcn_cvt_pk_f32_fp8)
#define HWFP8 1
#endif
#endif
__device__ __forceinline__ float fp8sw(unsigned char v) {
    unsigned e = (v >> 3) & 15u, m = v & 7u, s = v >> 7;
    float f = e ? __uint_as_float(((e + 120u) << 23) | (m << 20))
                : (float)m * 0.001953125f;
    return s ? -f : f;
}
__device__ __forceinline__ void dec4(unsigned int w, float* o) {
#ifdef HWFP8
    auto lo = __builtin_amdgcn_cvt_pk_f32_fp8(w, false);
    auto hi = __builtin_amdgcn_cvt_pk_f32_fp8(w, true);
    o[0] = lo[0]; o[1] = lo[1]; o[2] = hi[0]; o[3] = hi[1];
#else
    o[0] = fp8sw(w & 0xFF); o[1] = fp8sw((w >> 8) & 0xFF);
    o[2] = fp8sw((w >> 16) & 0xFF); o[3] = fp8sw(w >> 24);
#endif
}

// ---------------- one-time kernels ----------------

__global__ void k_cvt(const float4* __restrict__ in, ushort4* __restrict__ out, int n4) {
    int i = blockIdx.x * blockDim.x + threadIdx.x;
    int stride = gridDim.x * blockDim.x;
    for (; i < n4; i += stride) {
        float4 v = in[i];
        ushort4 u;
        u.x = f2bf(v.x); u.y = f2bf(v.y); u.z = f2bf(v.z); u.w = f2bf(v.w);
        out[i] = u;
    }
}

__global__ void k_cvt8(const float4* __restrict__ in, uchar4* __restrict__ out, int n4) {
    int i = blockIdx.x * blockDim.x + threadIdx.x;
    int stride = gridDim.x * blockDim.x;
    for (; i < n4; i += stride) {
        float4 v = in[i];
        uchar4 u;
        u.x = f2fp8(v.x); u.y = f2fp8(v.y); u.z = f2fp8(v.z); u.w = f2fp8(v.w);
        out[i] = u;
    }
}

__global__ __launch_bounds__(256) void k_init(
    const float* __restrict__ ef, const float* __restrict__ Wi,
    const float* __restrict__ bi, float* __restrict__ h0,
    unsigned short* __restrict__ hb16)
{
    __shared__ float efs[1024];
    int b = blockIdx.x, tid = threadIdx.x;
    for (int i = tid; i < 1024; i += 256) efs[i] = ef[(size_t)b * 1024 + i];
    __syncthreads();
    for (int j = tid; j < 512; j += 256) {
        const float4* w4 = (const float4*)(Wi + (size_t)j * 1024);
        float acc = 0.0f;
        for (int k4 = 0; k4 < 256; k4++) {
            float4 wv = w4[k4];
            int k = k4 << 2;
            acc = fmaf(efs[k],   wv.x, acc);
            acc = fmaf(efs[k+1], wv.y, acc);
            acc = fmaf(efs[k+2], wv.z, acc);
            acc = fmaf(efs[k+3], wv.w, acc);
        }
        float h = fast_tanh(acc + bi[j]);
        h0[(size_t)b * 512 + j] = h;
        hb16[(size_t)b * 512 + j] = f2bf(h);
    }
}

__global__ __launch_bounds__(512) void k_q0(
    const float* __restrict__ h, const float* __restrict__ Wq,
    float* __restrict__ qbuf)
{
    __shared__ float hs[512];
    int b = blockIdx.x, j = threadIdx.x;
    hs[j] = h[(size_t)b * 512 + j];
    __syncthreads();
    const float4* w4 = (const float4*)(Wq + (size_t)j * 512);
    float acc = 0.0f;
    #pragma unroll 4
    for (int k4 = 0; k4 < 128; k4++) {
        float4 wv = w4[k4];
        int k = k4 << 2;
        acc = fmaf(hs[k],   wv.x, acc);
        acc = fmaf(hs[k+1], wv.y, acc);
        acc = fmaf(hs[k+2], wv.z, acc);
        acc = fmaf(hs[k+3], wv.w, acc);
    }
    qbuf[(size_t)b * 512 + j] = acc;
}

// MFMA bf16 GEMM: C[M][N] = A[M][K] @ B[N][K]^T.
// A: either fp32 single segment (Af, ld0) or bf16 in up to 3 row-major
// segments (A0/A1/A2, boundaries s1/s2). Output: fp32 Cf, bf16 Cb, or fp8 C8.
__global__ __launch_bounds__(256) void k_mfma_gemm(
    const float* __restrict__ Af,
    const unsigned short* __restrict__ A0, const unsigned short* __restrict__ A1,
    const unsigned short* __restrict__ A2,
    int ld0, int ld1, int ld2, int s1, int s2,
    const unsigned short* __restrict__ Bw, int ldb,
    float* __restrict__ Cf, unsigned short* __restrict__ Cb,
    unsigned char* __restrict__ C8, int ldc,
    const float* __restrict__ bias, int K)
{
    __shared__ __attribute__((aligned(16))) unsigned short As[128][40];
    __shared__ __attribute__((aligned(16))) unsigned short Bs[128][40];
    int m0 = blockIdx.x << 7, n0 = blockIdx.y << 7;
    int tid = threadIdx.x;
    int wave = tid >> 6, lane = tid & 63;
    int wr = (wave >> 1) << 6, wc = (wave & 1) << 6;
    int fr = lane & 15, fq = lane >> 4;
    f32x4 acc[4][4];
    #pragma unroll
    for (int i = 0; i < 4; i++)
        #pragma unroll
        for (int j = 0; j < 4; j++)
            acc[i][j] = (f32x4){0.f, 0.f, 0.f, 0.f};
    int lrow = tid >> 1;
    int lk = (tid & 1) << 4;
    for (int k0 = 0; k0 < K; k0 += 32) {
        u16x8 av0, av1;
        if (Af) {
            const float* ap = Af + (size_t)(m0 + lrow) * ld0 + k0 + lk;
            float4 f0 = *(const float4*)ap;
            float4 f1 = *(const float4*)(ap + 4);
            float4 f2 = *(const float4*)(ap + 8);
            float4 f3 = *(const float4*)(ap + 12);
            av0[0]=f2bf(f0.x); av0[1]=f2bf(f0.y); av0[2]=f2bf(f0.z); av0[3]=f2bf(f0.w);
            av0[4]=f2bf(f1.x); av0[5]=f2bf(f1.y); av0[6]=f2bf(f1.z); av0[7]=f2bf(f1.w);
            av1[0]=f2bf(f2.x); av1[1]=f2bf(f2.y); av1[2]=f2bf(f2.z); av1[3]=f2bf(f2.w);
            av1[4]=f2bf(f3.x); av1[5]=f2bf(f3.y); av1[6]=f2bf(f3.z); av1[7]=f2bf(f3.w);
        } else {
            const unsigned short* Ap; int lda_, ka;
            if (k0 < s1)      { Ap = A0; lda_ = ld0; ka = k0; }
            else if (k0 < s2) { Ap = A1; lda_ = ld1; ka = k0 - s1; }
            else              { Ap = A2; lda_ = ld2; ka = k0 - s2; }
            const unsigned short* ap = Ap + (size_t)(m0 + lrow) * lda_ + ka + lk;
            av0 = *(const u16x8*)ap;
            av1 = *(const u16x8*)(ap + 8);
        }
        const unsigned short* bp_ = Bw + (size_t)(n0 + lrow) * ldb + k0 + lk;
        u16x8 bv0 = *(const u16x8*)bp_;
        u16x8 bv1 = *(const u16x8*)(bp_ + 8);
        __syncthreads();
        *(u16x8*)&As[lrow][lk] = av0;
        *(u16x8*)&As[lrow][lk + 8] = av1;
        *(u16x8*)&Bs[lrow][lk] = bv0;
        *(u16x8*)&Bs[lrow][lk + 8] = bv1;
        __syncthreads();
        bf16x8 af[4], bf[4];
        #pragma unroll
        for (int i = 0; i < 4; i++) {
            af[i] = *(const bf16x8*)&As[wr + (i << 4) + fr][fq << 3];
            bf[i] = *(const bf16x8*)&Bs[wc + (i << 4) + fr][fq << 3];
        }
        #pragma unroll
        for (int i = 0; i < 4; i++)
            #pragma unroll
            for (int j = 0; j < 4; j++)
                acc[i][j] = __builtin_amdgcn_mfma_f32_16x16x32_bf16(af[i], bf[j], acc[i][j], 0, 0, 0);
    }
    #pragma unroll
    for (int j = 0; j < 4; j++) {
        int col = n0 + wc + (j << 4) + fr;
        float bv = bias ? bias[col] : 0.0f;
        #pragma unroll
        for (int i = 0; i < 4; i++) {
            int rbase = m0 + wr + (i << 4) + (fq << 2);
            #pragma unroll
            for (int r = 0; r < 4; r++) {
                float v = acc[i][j][r] + bv;
                if (C8)      C8[(size_t)(rbase + r) * ldc + col] = f2fp8(v);
                else if (Cb) Cb[(size_t)(rbase + r) * ldc + col] = f2bf(v);
                else         Cf[(size_t)(rbase + r) * ldc + col] = v;
            }
        }
    }
}

// ---------------- per-step kernels ----------------

// K1: energies (fp8 pkb) + no-max softmax + context partials (fp8 ehb).
// 512 blocks: c = bid>>6 (8 chunks of 50 s), b = bid&63. 256 threads.
__global__ __launch_bounds__(256) void k_attn(
    const unsigned char* __restrict__ pkb8, const unsigned char* __restrict__ ehb8,
    const float* __restrict__ qbuf, const float* __restrict__ We,
    float* __restrict__ ctxp, float* __restrict__ sumc)
{
    int bid = blockIdx.x;
    int c = bid >> 6, b = bid & 63;
    int s0 = c * 50;
    int tid = threadIdx.x, wave = tid >> 6, lane = tid & 63;
    __shared__ float eL[52], pL[52];

    float q8[8], w8[8];
    {
        const float4* qp = (const float4*)(qbuf + (size_t)b * 512 + (lane << 3));
        float4 q0 = qp[0], q1 = qp[1];
        q8[0]=q0.x; q8[1]=q0.y; q8[2]=q0.z; q8[3]=q0.w;
        q8[4]=q1.x; q8[5]=q1.y; q8[6]=q1.z; q8[7]=q1.w;
        const float4* wp = (const float4*)(We + (lane << 3));
        float4 w0 = wp[0], w1 = wp[1];
        w8[0]=w0.x; w8[1]=w0.y; w8[2]=w0.z; w8[3]=w0.w;
        w8[4]=w1.x; w8[5]=w1.y; w8[6]=w1.z; w8[7]=w1.w;
    }
    // phase A: energies, one wave per s row
    for (int sl = wave; sl < 50; sl += 4) {
        const unsigned char* pr = pkb8 + ((size_t)(b * Sdim + s0 + sl) << 9) + (lane << 3);
        uint2 u = *(const uint2*)pr;
        float p[8];
        dec4(u.x, p); dec4(u.y, p + 4);
        float sum = 0.0f;
        #pragma unroll
        for (int jj = 0; jj < 8; jj++)
            sum = fmaf(fast_tanh(q8[jj] + p[jj]), w8[jj], sum);
        #pragma unroll
        for (int off = 32; off > 0; off >>= 1) sum += __shfl_xor(sum, off, 64);
        if (lane == 0) eL[sl] = sum;
    }
    __syncthreads();
    // phase B: p = exp(e) (energies bounded, no max needed), chunk sum
    if (wave == 0) {
        float pv = 0.0f;
        if (lane < 50) { pv = __expf(eL[lane]); pL[lane] = pv; }
        float s = pv;
        #pragma unroll
        for (int off = 32; off > 0; off >>= 1) s += __shfl_xor(s, off, 64);
        if (lane == 0) sumc[b * 8 + c] = s;
    }
    __syncthreads();
    // phase C: unnormalized context partial; thread owns 4 dims
    int d0 = tid << 2;
    float a0 = 0.f, a1 = 0.f, a2 = 0.f, a3 = 0.f;
    const unsigned char* eb = ehb8 + ((size_t)(b * Sdim + s0) << 10) + d0;
    for (int sl = 0; sl < 50; sl++) {
        float pp = pL[sl];
        unsigned int u = *(const unsigned int*)(eb + ((size_t)sl << 10));
        float v[4];
        dec4(u, v);
        a0 = fmaf(pp, v[0], a0);
        a1 = fmaf(pp, v[1], a1);
        a2 = fmaf(pp, v[2], a2);
        a3 = fmaf(pp, v[3], a3);
    }
    *(float4*)&ctxp[((size_t)(b * 8 + c) << 10) + d0] = make_float4(a0, a1, a2, a3);
}

// K2: MFMA GRU GEMMs with fused chunk-combine.
// 144 blocks x 512 thr: 0..95 gi-ctx (4 K-chunks x 24 N), 96..143 gh (2 x 24).
__global__ __launch_bounds__(512) void k_mm(
    const float* __restrict__ ctxp, const float* __restrict__ sumc,
    const unsigned short* __restrict__ hb16,
    const unsigned short* __restrict__ Wihb, const unsigned short* __restrict__ Whhb,
    float* __restrict__ pgi, float* __restrict__ pgh,
    unsigned short* __restrict__ csb, int t)
{
    __shared__ __attribute__((aligned(16))) unsigned short As[64][264];
    __shared__ __attribute__((aligned(16))) unsigned short Ws[64][72];
    int bid = blockIdx.x, tid = threadIdx.x;
    int wave = tid >> 6, lane = tid & 63;
    bool isGi = bid < 96;
    int kc, nb;
    if (isGi) { kc = bid / 24; nb = bid - kc * 24; }
    else      { int x = bid - 96; kc = x / 24; nb = x - kc * 24; }
    int n0 = nb << 6;

    int r = tid >> 3, c0 = (tid & 7) << 5;
    if (isGi) {
        const float* sc = sumc + r * 8;
        float inv = 1.0f / (sc[0]+sc[1]+sc[2]+sc[3]+sc[4]+sc[5]+sc[6]+sc[7]);
        const float* pc = ctxp + ((size_t)r << 13) + (kc << 8) + c0;
        #pragma unroll
        for (int k4 = 0; k4 < 8; k4++) {
            float ax = 0.f, ay = 0.f, az = 0.f, aw = 0.f;
            #pragma unroll
            for (int cc = 0; cc < 8; cc++) {
                float4 v = *(const float4*)(pc + (cc << 10) + (k4 << 2));
                ax += v.x; ay += v.y; az += v.z; aw += v.w;
            }
            ushort4 u;
            u.x = f2bf(ax * inv); u.y = f2bf(ay * inv);
            u.z = f2bf(az * inv); u.w = f2bf(aw * inv);
            *(ushort4*)&As[r][c0 + (k4 << 2)] = u;
            if (nb == 0)
                *(ushort4*)&csb[((size_t)(r * Tdim + t) << 10) + (kc << 8) + c0 + (k4 << 2)] = u;
        }
    } else {
        const unsigned short* ph = hb16 + (size_t)r * 512 + (kc << 8) + c0;
        *(u16x8*)&As[r][c0]      = *(const u16x8*)ph;
        *(u16x8*)&As[r][c0 + 8]  = *(const u16x8*)(ph + 8);
        *(u16x8*)&As[r][c0 + 16] = *(const u16x8*)(ph + 16);
        *(u16x8*)&As[r][c0 + 24] = *(const u16x8*)(ph + 24);
    }
    __syncthreads();

    const unsigned short* Wsrc = isGi ? (Wihb + (size_t)n0 * H3 + 512 + (kc << 8))
                                      : (Whhb + (size_t)n0 * Hdim + (kc << 8));
    int ldw = isGi ? H3 : Hdim;
    int fr = lane & 15, fq = lane >> 4;
    int fi = wave >> 1, fj0 = (wave & 1) << 1;
    f32x4 acc0 = {0.f,0.f,0.f,0.f}, acc1 = {0.f,0.f,0.f,0.f};
    int rw = tid >> 3, cw2 = (tid & 7) << 3;
    for (int ch = 0; ch < 4; ch++) {
        __syncthreads();
        u16x8 wv8 = *(const u16x8*)(Wsrc + (size_t)rw * ldw + (ch << 6) + cw2);
        *(u16x8*)&Ws[rw][cw2] = wv8;
        __syncthreads();
        #pragma unroll
        for (int ks = 0; ks < 2; ks++) {
            bf16x8 af = *(const bf16x8*)&As[(fi << 4) + fr][(ch << 6) + (ks << 5) + (fq << 3)];
            bf16x8 b0 = *(const bf16x8*)&Ws[(fj0 << 4) + fr][(ks << 5) + (fq << 3)];
            bf16x8 b1 = *(const bf16x8*)&Ws[((fj0 + 1) << 4) + fr][(ks << 5) + (fq << 3)];
            acc0 = __builtin_amdgcn_mfma_f32_16x16x32_bf16(af, b0, acc0, 0, 0, 0);
            acc1 = __builtin_amdgcn_mfma_f32_16x16x32_bf16(af, b1, acc1, 0, 0, 0);
        }
    }
    float* outp = (isGi ? pgi : pgh) + (size_t)kc * Bdim * H3;
    int rowb = (fi << 4) + (fq << 2);
    #pragma unroll
    for (int r4 = 0; r4 < 4; r4++) {
        outp[(size_t)(rowb + r4) * H3 + n0 + (fj0 << 4) + fr] = acc0[r4];
        outp[(size_t)(rowb + r4) * H3 + n0 + ((fj0 + 1) << 4) + fr] = acc1[r4];
    }
}

// K3: reduce partials (+hoisted gi_embed) + GRU gates + h_new + q_{t+1}
__global__ __launch_bounds__(512) void k_gates(
    const float* __restrict__ pgi, const float* __restrict__ pgh,
    const unsigned short* __restrict__ giEb,
    const float* __restrict__ bih, const float* __restrict__ bhh,
    float* __restrict__ hbuf,
    const unsigned short* __restrict__ Wqb, float* __restrict__ qbuf,
    float* __restrict__ ds, unsigned short* __restrict__ dsb,
    unsigned short* __restrict__ hb16, float* __restrict__ hlast, int t)
{
    int b = blockIdx.x, j = threadIdx.x;
    size_t m = (size_t)b * Tdim + t;
    float gir = 0, giz = 0, gin = 0;
    #pragma unroll
    for (int cc = 0; cc < 4; cc++) {
        const float* p = pgi + ((size_t)cc * Bdim + b) * H3;
        gir += p[j]; giz += p[j + 512]; gin += p[j + 1024];
    }
    const unsigned short* ge = giEb + m * H3;
    gir += bf2f(ge[j]); giz += bf2f(ge[j + 512]); gin += bf2f(ge[j + 1024]);
    float ghr = 0, ghz = 0, ghn = 0;
    #pragma unroll
    for (int cc = 0; cc < 2; cc++) {
        const float* p = pgh + ((size_t)cc * Bdim + b) * H3;
        ghr += p[j]; ghz += p[j + 512]; ghn += p[j + 1024];
    }
    gir += bih[j];        ghr += bhh[j];
    giz += bih[j + 512];  ghz += bhh[j + 512];
    gin += bih[j + 1024]; ghn += bhh[j + 1024];
    float rg = sigm(gir + ghr);
    float z  = sigm(giz + ghz);
    float nn = fast_tanh(gin + rg * ghn);
    float hp = hbuf[(size_t)b * 512 + j];
    float hn = (1.0f - z) * nn + z * hp;
    ds[m * 512 + j] = hn;
    dsb[m * 512 + j] = f2bf(hn);
    hb16[(size_t)b * 512 + j] = f2bf(hn);
    hbuf[(size_t)b * 512 + j] = hn;
    if (t == Tdim - 1) hlast[(size_t)b * 512 + j] = hn;
    // q_{t+1} = h_new @ W_query.T  (bf16 weights; L2-dedup across the 64 blocks)
    __shared__ float hs[512];
    hs[j] = hn;
    __syncthreads();
    const unsigned short* wr_ = Wqb + (size_t)j * 512;
    float acc = 0.0f;
    #pragma unroll 4
    for (int k8 = 0; k8 < 64; k8++) {
        u16x8 wv = *(const u16x8*)(wr_ + (k8 << 3));
        int k = k8 << 3;
        acc = fmaf(hs[k],   bf2f(wv[0]), acc);
        acc = fmaf(hs[k+1], bf2f(wv[1]), acc);
        acc = fmaf(hs[k+2], bf2f(wv[2]), acc);
        acc = fmaf(hs[k+3], bf2f(wv[3]), acc);
        acc = fmaf(hs[k+4], bf2f(wv[4]), acc);
        acc = fmaf(hs[k+5], bf2f(wv[5]), acc);
        acc = fmaf(hs[k+6], bf2f(wv[6]), acc);
        acc = fmaf(hs[k+7], bf2f(wv[7]), acc);
    }
    qbuf[(size_t)b * 512 + j] = acc;
}

extern "C" void kernel_launch(void* const* d_in, const int* in_sizes, int n_in,
                              void* d_out, int out_size, void* d_ws, size_t ws_size,
                              hipStream_t stream) {
    const float* te  = (const float*)d_in[0];
    const float* eh  = (const float*)d_in[1];
    const float* ef  = (const float*)d_in[2];
    const float* Wi  = (const float*)d_in[3];
    const float* bi  = (const float*)d_in[4];
    const float* Wk  = (const float*)d_in[5];
    const float* Wq  = (const float*)d_in[6];
    const float* We  = (const float*)d_in[7];
    const float* Wih = (const float*)d_in[8];
    const float* Whh = (const float*)d_in[9];
    const float* bih = (const float*)d_in[10];
    const float* bhh = (const float*)d_in[11];
    const float* Wp  = (const float*)d_in[12];
    const float* bp  = (const float*)d_in[13];

    float* out     = (float*)d_out;
    float* out_ds  = out;
    float* out_hl  = out + (size_t)Bdim * Tdim * Hdim;
    float* out_pre = out_hl + (size_t)Bdim * Hdim;

    // ---- workspace (~100 MiB) ----
    char* w = (char*)d_ws;
    size_t o = 0;
    unsigned char*  pkb8 = (unsigned char*)(w + o);  o += (size_t)25600 * 512;       // fp8
    unsigned char*  ehb8 = (unsigned char*)(w + o);  o += (size_t)25600 * 1024;      // fp8
    unsigned short* teb  = (unsigned short*)(w + o); o += (size_t)6400 * 512 * 2;
    unsigned short* Wkb  = (unsigned short*)(w + o); o += (size_t)512 * 1024 * 2;
    unsigned short* Wihb = (unsigned short*)(w + o); o += (size_t)1536 * 1536 * 2;
    unsigned short* Whhb = (unsigned short*)(w + o); o += (size_t)1536 * 512 * 2;
    unsigned short* Wpb  = (unsigned short*)(w + o); o += (size_t)512 * 2048 * 2;
    unsigned short* Wqb  = (unsigned short*)(w + o); o += (size_t)512 * 512 * 2;
    unsigned short* dsb  = (unsigned short*)(w + o); o += (size_t)6400 * 512 * 2;
    unsigned short* csb  = (unsigned short*)(w + o); o += (size_t)6400 * 1024 * 2;
    unsigned short* giEb = (unsigned short*)(w + o); o += (size_t)6400 * 1536 * 2;
    unsigned short* hb16 = (unsigned short*)(w + o); o += (size_t)Bdim * 512 * 2;
    float* qbuf = (float*)(w + o); o += (size_t)Bdim * 512 * 4;
    float* hbuf = (float*)(w + o); o += (size_t)Bdim * 512 * 4;
    float* ctxp = (float*)(w + o); o += (size_t)Bdim * 8 * 1024 * 4;
    float* sumc = (float*)(w + o); o += 512 * 4;
    float* pgi  = (float*)(w + o); o += (size_t)4 * Bdim * H3 * 4;
    float* pgh  = (float*)(w + o); o += (size_t)2 * Bdim * H3 * 4;

    // ---- one-time prep ----
    k_cvt8<<<2048, 256, 0, stream>>>((const float4*)eh, (uchar4*)ehb8, 6553600);
    k_cvt<<<512,  256, 0, stream>>>((const float4*)te,  (ushort4*)teb,  819200);
    k_cvt<<<128,  256, 0, stream>>>((const float4*)Wk,  (ushort4*)Wkb,  131072);
    k_cvt<<<256,  256, 0, stream>>>((const float4*)Wih, (ushort4*)Wihb, 589824);
    k_cvt<<<128,  256, 0, stream>>>((const float4*)Whh, (ushort4*)Whhb, 196608);
    k_cvt<<<256,  256, 0, stream>>>((const float4*)Wp,  (ushort4*)Wpb,  262144);
    k_cvt<<<64,   256, 0, stream>>>((const float4*)Wq,  (ushort4*)Wqb,  65536);
    k_init<<<Bdim, 256, 0, stream>>>(ef, Wi, bi, hbuf, hb16);
    k_q0<<<Bdim, 512, 0, stream>>>(hbuf, Wq, qbuf);
    // proj_key = eh(f32) @ Wkb^T -> pkb8 (fp8), M=25600 N=512 K=1024
    k_mfma_gemm<<<dim3(200, 4), 256, 0, stream>>>(
        eh, nullptr, nullptr, nullptr, 1024, 0, 0, 1024, 1024,
        Wkb, 1024, nullptr, nullptr, pkb8, 512, nullptr, 1024);
    // gi_embed = teb @ Wihb[:, :512]^T -> giEb (bf16), M=6400 N=1536 K=512
    k_mfma_gemm<<<dim3(50, 12), 256, 0, stream>>>(
        nullptr, teb, teb, teb, 512, 512, 512, 512, 512,
        Wihb, 1536, nullptr, giEb, nullptr, 1536, nullptr, 512);

    // ---- scan over T: 3 kernels/step ----
    for (int t = 0; t < Tdim; t++) {
        k_attn<<<512, 256, 0, stream>>>(pkb8, ehb8, qbuf, We, ctxp, sumc);
        k_mm<<<144, 512, 0, stream>>>(ctxp, sumc, hb16, Wihb, Whhb, pgi, pgh, csb, t);
        k_gates<<<Bdim, 512, 0, stream>>>(pgi, pgh, giEb, bih, bhh, hbuf,
                                          Wqb, qbuf, out_ds, dsb, hb16, out_hl, t);
    }

    // ---- final: pre = [teb | dsb | csb] @ Wpb^T + bp, M=6400 N=512 K=2048 ----
    k_mfma_gemm<<<dim3(50, 4), 256, 0, stream>>>(
        nullptr, teb, dsb, csb, 512, 512, 1024, 512, 1024,
        Wpb, 2048, out_pre, nullptr, nullptr, 512, bp, 2048);
}